// Round 1
// baseline (240.521 us; speedup 1.0000x reference)
//
#include <hip/hip_runtime.h>
#include <hip/hip_bf16.h>

// Problem constants (from reference): B=4, S=4096, D=2048, K=4
// x: [B,S,D] fp32, weight: [D,1,K] fp32, bias: [D] fp32, out: [B,S,D] fp32
// out[b,s,d] = bias[d] + sum_k w[d,k] * x[b, s-3+k, d]   (zero-pad s<0)

namespace {
constexpr int B = 4;
constexpr int S = 4096;
constexpr int D = 2048;
constexpr int D4 = D / 4;        // 512 float4 per row
constexpr int R = 16;            // s-rows per thread (rolling window)
constexpr int BLOCK = 256;
}

__global__ __launch_bounds__(BLOCK) void causal_dwconv1d_k4(
    const float4* __restrict__ x,      // [B*S*D4]
    const float4* __restrict__ w4,     // [D] : w4[d] = {w[d,0],w[d,1],w[d,2],w[d,3]}
    const float4* __restrict__ bias4,  // [D4]
    float4* __restrict__ out)          // [B*S*D4]
{
    const int d4 = blockIdx.x * BLOCK + threadIdx.x;   // 0..D4-1
    const int s0 = blockIdx.y * R;
    const int b  = blockIdx.z;

    // Per-channel weights: channel d = d4*4 + j, j = component of the float4.
    const float4 wa = w4[d4 * 4 + 0];
    const float4 wb = w4[d4 * 4 + 1];
    const float4 wc = w4[d4 * 4 + 2];
    const float4 wd = w4[d4 * 4 + 3];
    const float4 bv = bias4[d4];

    const float4* xb = x   + (size_t)b * S * D4;
    float4*       ob = out + (size_t)b * S * D4;

    const float4 zero = make_float4(0.f, 0.f, 0.f, 0.f);
    float4 xm3 = (s0 - 3 >= 0) ? xb[(size_t)(s0 - 3) * D4 + d4] : zero;
    float4 xm2 = (s0 - 2 >= 0) ? xb[(size_t)(s0 - 2) * D4 + d4] : zero;
    float4 xm1 = (s0 - 1 >= 0) ? xb[(size_t)(s0 - 1) * D4 + d4] : zero;

#pragma unroll
    for (int r = 0; r < R; ++r) {
        const int s = s0 + r;
        const float4 xc = xb[(size_t)s * D4 + d4];
        float4 o;
        o.x = bv.x + wa.x * xm3.x + wa.y * xm2.x + wa.z * xm1.x + wa.w * xc.x;
        o.y = bv.y + wb.x * xm3.y + wb.y * xm2.y + wb.z * xm1.y + wb.w * xc.y;
        o.z = bv.z + wc.x * xm3.z + wc.y * xm2.z + wc.z * xm1.z + wc.w * xc.z;
        o.w = bv.w + wd.x * xm3.w + wd.y * xm2.w + wd.z * xm1.w + wd.w * xc.w;
        ob[(size_t)s * D4 + d4] = o;
        xm3 = xm2;
        xm2 = xm1;
        xm1 = xc;
    }
}

extern "C" void kernel_launch(void* const* d_in, const int* in_sizes, int n_in,
                              void* d_out, int out_size, void* d_ws, size_t ws_size,
                              hipStream_t stream) {
    const float4* x     = (const float4*)d_in[0];
    const float4* w4    = (const float4*)d_in[1];   // [D,1,K] = [D][4] floats
    const float4* bias4 = (const float4*)d_in[2];
    float4* out         = (float4*)d_out;

    dim3 grid(D4 / BLOCK, S / R, B);   // (2, 256, 4)
    dim3 block(BLOCK);
    causal_dwconv1d_k4<<<grid, block, 0, stream>>>(x, w4, bias4, out);
}

// Round 3
// 238.821 us; speedup vs baseline: 1.0071x; 1.0071x over previous
//
#include <hip/hip_runtime.h>
#include <hip/hip_bf16.h>

// Problem constants (from reference): B=4, S=4096, D=2048, K=4
// x: [B,S,D] fp32, weight: [D,1,K] fp32, bias: [D] fp32, out: [B,S,D] fp32
// out[b,s,d] = bias[d] + sum_k w[d,k] * x[b, s-3+k, d]   (zero-pad s<0)

typedef float vfloat4 __attribute__((ext_vector_type(4)));  // native vec for builtins

namespace {
constexpr int B = 4;
constexpr int S = 4096;
constexpr int D = 2048;
constexpr int D4 = D / 4;        // 512 vfloat4 per row
constexpr int R = 16;            // s-rows per thread
constexpr int BLOCK = 256;
}

__global__ __launch_bounds__(BLOCK) void causal_dwconv1d_k4(
    const vfloat4* __restrict__ x,      // [B*S*D4]
    const vfloat4* __restrict__ w4,     // [D] : w4[d] = {w[d,0..3]}
    const vfloat4* __restrict__ bias4,  // [D4]
    vfloat4* __restrict__ out)          // [B*S*D4]
{
    const int d4 = blockIdx.x * BLOCK + threadIdx.x;   // 0..D4-1
    const int s0 = blockIdx.y * R;
    const int b  = blockIdx.z;

    const vfloat4* xb = x   + (size_t)b * S * D4 + d4;
    vfloat4*       ob = out + (size_t)b * S * D4 + d4;

    const vfloat4 zero = (vfloat4)(0.f);

    // Prefetch all R+3 rows up-front: 19 independent global_load_dwordx4 in
    // flight per wave -> deep MLP instead of a serialized rolling window.
    vfloat4 xr[R + 3];
    if (s0 >= 3) {
#pragma unroll
        for (int i = 0; i < R + 3; ++i)
            xr[i] = xb[(size_t)(s0 - 3 + i) * D4];
    } else {
#pragma unroll
        for (int i = 0; i < R + 3; ++i) {
            const int s = s0 - 3 + i;
            xr[i] = (s >= 0) ? xb[(size_t)s * D4] : zero;
        }
    }

    // Per-channel weights (small, L2-resident).
    const vfloat4 wa = w4[d4 * 4 + 0];
    const vfloat4 wb = w4[d4 * 4 + 1];
    const vfloat4 wc = w4[d4 * 4 + 2];
    const vfloat4 wd = w4[d4 * 4 + 3];
    const vfloat4 bv = bias4[d4];

#pragma unroll
    for (int r = 0; r < R; ++r) {
        const vfloat4 xm3 = xr[r + 0];
        const vfloat4 xm2 = xr[r + 1];
        const vfloat4 xm1 = xr[r + 2];
        const vfloat4 xc  = xr[r + 3];
        vfloat4 o;
        o.x = bv.x + wa.x * xm3.x + wa.y * xm2.x + wa.z * xm1.x + wa.w * xc.x;
        o.y = bv.y + wb.x * xm3.y + wb.y * xm2.y + wb.z * xm1.y + wb.w * xc.y;
        o.z = bv.z + wc.x * xm3.z + wc.y * xm2.z + wc.z * xm1.z + wc.w * xc.z;
        o.w = bv.w + wd.x * xm3.w + wd.y * xm2.w + wd.z * xm1.w + wd.w * xc.w;
        // Non-temporal store: out is write-once streaming; keep x in L2/LLC.
        __builtin_nontemporal_store(o, &ob[(size_t)(s0 + r) * D4]);
    }
}

extern "C" void kernel_launch(void* const* d_in, const int* in_sizes, int n_in,
                              void* d_out, int out_size, void* d_ws, size_t ws_size,
                              hipStream_t stream) {
    const vfloat4* x     = (const vfloat4*)d_in[0];
    const vfloat4* w4    = (const vfloat4*)d_in[1];
    const vfloat4* bias4 = (const vfloat4*)d_in[2];
    vfloat4* out         = (vfloat4*)d_out;

    dim3 grid(D4 / BLOCK, S / R, B);   // (2, 256, 4) = 2048 blocks
    dim3 block(BLOCK);
    causal_dwconv1d_k4<<<grid, block, 0, stream>>>(x, w4, bias4, out);
}